// Round 5
// baseline (225.552 us; speedup 1.0000x reference)
//
#include <hip/hip_runtime.h>
#include <math.h>

#define NSAMP 32768
#define FS_F 44100.0f
#define PI_F 3.14159265358979323846f

struct BParams {
  float alpha, alpha_p;
  float fr, g, s;
  int Di;
  float lc, lm, lp;
};

__device__ inline float sigmoidf_(float x) { return 1.0f / (1.0f + expf(-x)); }

__device__ inline BParams compute_params(int b, const float* __restrict__ pitch,
                                         const float* __restrict__ w1,
                                         const float* __restrict__ b1,
                                         const float* __restrict__ w2,
                                         const float* __restrict__ b2) {
  BParams P;
  float p = pitch[b];
  float h[16];
#pragma unroll
  for (int i = 0; i < 16; ++i) {
    float v = fmaf(p, w1[i], b1[i]);
    h[i] = v > 0.0f ? v : 0.0f;
  }
  float m[3];
#pragma unroll
  for (int j = 0; j < 3; ++j) {
    float acc = b2[j];
#pragma unroll
    for (int i = 0; i < 16; ++i) acc = fmaf(h[i], w2[j * 16 + i], acc);
    m[j] = acc;
  }
  P.lc = fminf(fmaxf(m[0], -2.0f), 2.5f);
  P.lm = fminf(fmaxf(m[1], -2.5f), 0.0f);
  P.lp = fminf(fmaxf(m[2], -4.0f), 4.0f);
  P.g = 0.999f * sigmoidf_(P.lc);
  P.s = sigmoidf_(P.lm);
  float f0 = fmaxf(p, 60.0f);
  float D = fminf(fmaxf(FS_F / f0, 2.0f), 735.0f);
  int Di = (int)floorf(D);
  P.fr = D - (float)Di;
  P.Di = Di;
  float mult = fminf(fmaxf(2.0f + 6.0f * (f0 - 60.0f) / 600.0f, 2.0f), 8.0f);
  float cutoff = fminf(2.0f * PI_F * f0 * mult / FS_F, PI_F * 0.9f);
  P.alpha = 1.0f - expf(-cutoff);
  float cpost = fminf(PI_F * sigmoidf_(P.lp), PI_F * 0.99f);
  P.alpha_p = 1.0f - expf(-cpost);
  return P;
}

// lane helpers (wave64)
__device__ inline float rl63(float v) {
  return __int_as_float(__builtin_amdgcn_readlane(__float_as_int(v), 63));
}
__device__ inline float rlv(float v, int l) {
  return __int_as_float(__builtin_amdgcn_readlane(__float_as_int(v), l));
}
// whole-wave shift right by 1; lane 0 takes `bnd` (uniform value)
__device__ inline float shr1(float v, float bnd) {
  return __int_as_float(__builtin_amdgcn_update_dpp(
      __float_as_int(bnd), __float_as_int(v), 0x138 /*wave_shr:1*/, 0xf, 0xf,
      false));
}

// Exact one-pole IIR y[n] = scale*x[n] + c*y[n-1] over NSAMP, 256 threads.
__device__ inline void lpc_scan2(const float* __restrict__ in,
                                 float* __restrict__ out, float scale, float c,
                                 int t, float* lws) {
  const int lane = t & 63, wid = t >> 6;
  float c2v = c * c, c4 = c2v * c2v, c8 = c4 * c4;
  float m1 = c8, m2 = m1 * m1, m4 = m2 * m2, m8 = m4 * m4, m16 = m8 * m8,
        m32 = m16 * m16;
  float c512 = m32 * m32;
  float c2048 = c512 * c512;
  c2048 *= c2048;
  float l2c = log2f(c);
  float c8lane = exp2f((float)(8 * lane) * l2c);
  float cgk = exp2f((float)(8 * t) * l2c);
  float vrun = 0.0f;
  const float4* in4 = (const float4*)in;
  float4* out4 = (float4*)out;
  for (int tile = 0; tile < 16; ++tile) {
    __syncthreads();  // lws reuse guard
    float4 xa = in4[(tile << 9) + 2 * t];
    float4 xb = in4[(tile << 9) + 2 * t + 1];
    float S = 0.0f;
    S = fmaf(c, S, scale * xa.x);
    S = fmaf(c, S, scale * xa.y);
    S = fmaf(c, S, scale * xa.z);
    S = fmaf(c, S, scale * xa.w);
    S = fmaf(c, S, scale * xb.x);
    S = fmaf(c, S, scale * xb.y);
    S = fmaf(c, S, scale * xb.z);
    S = fmaf(c, S, scale * xb.w);
    float Sw = S, u;
    u = __shfl_up(Sw, 1);
    if (lane >= 1) Sw = fmaf(m1, u, Sw);
    u = __shfl_up(Sw, 2);
    if (lane >= 2) Sw = fmaf(m2, u, Sw);
    u = __shfl_up(Sw, 4);
    if (lane >= 4) Sw = fmaf(m4, u, Sw);
    u = __shfl_up(Sw, 8);
    if (lane >= 8) Sw = fmaf(m8, u, Sw);
    u = __shfl_up(Sw, 16);
    if (lane >= 16) Sw = fmaf(m16, u, Sw);
    u = __shfl_up(Sw, 32);
    if (lane >= 32) Sw = fmaf(m32, u, Sw);
    if (lane == 63) lws[wid] = Sw;
    __syncthreads();
    float a0 = lws[0], a1w = lws[1], a2w = lws[2], a3w = lws[3];
    float carry = (wid == 1)   ? a0
                  : (wid == 2) ? fmaf(c512, a0, a1w)
                  : (wid == 3) ? fmaf(c512, fmaf(c512, a0, a1w), a2w)
                               : 0.0f;
    float Sprev = __shfl_up(Sw, 1);
    float Sex = (lane == 0) ? 0.0f : Sprev;
    Sex = fmaf(c8lane, carry, Sex);
    float v = fmaf(cgk, vrun, Sex);
    float4 ya, yb;
    v = fmaf(c, v, scale * xa.x); ya.x = v;
    v = fmaf(c, v, scale * xa.y); ya.y = v;
    v = fmaf(c, v, scale * xa.z); ya.z = v;
    v = fmaf(c, v, scale * xa.w); ya.w = v;
    v = fmaf(c, v, scale * xb.x); yb.x = v;
    v = fmaf(c, v, scale * xb.y); yb.y = v;
    v = fmaf(c, v, scale * xb.z); yb.z = v;
    v = fmaf(c, v, scale * xb.w); yb.w = v;
    out4[(tile << 9) + 2 * t] = ya;
    out4[(tile << 9) + 2 * t + 1] = yb;
    float tS = fmaf(c512, fmaf(c512, fmaf(c512, a0, a1w), a2w), a3w);
    vrun = fmaf(c2048, vrun, tS);
  }
}

// KS with compile-time slot count (see R4). Wave 0 register-resident chunk
// recurrence; waves 1-3 stream xg->xbuf and yring->yg.
template <int KNUM>
__device__ void ks_run(const float* __restrict__ xg, float* __restrict__ yg,
                       float* xbuf, float* yring, int t, int C, float c0w,
                       float c1w, float c2w) {
  const int lane = t & 63;
  float yp[KNUM], xA[KNUM], xB[KNUM], xC[KNUM], xD[KNUM];
  int vx[KNUM], vy[KNUM];
  float p1 = 0.0f, p2 = 0.0f;  // y[n0-C-1], y[n0-C-2]
  int n0 = 0;
  const int lq1 = (C - 1) - (KNUM - 1) * 64;     // lane of y(C-1) in last slot
  const bool wr = (lane + (KNUM - 1) * 64) < C;  // last-slot store guard

  for (int s = 0; s < 16; ++s) {
    __syncthreads();
    if (t < 64) {
      if (s == 0) {
#pragma unroll
        for (int k = 0; k < KNUM; ++k) {
          int i = lane + (k << 6);
          yp[k] = 0.0f;
          xA[k] = xbuf[i];
          xB[k] = xbuf[i + C];
          xC[k] = xbuf[i + 2 * C];
          xD[k] = xbuf[i + 3 * C];
          vx[k] = (i + 4 * C) & 8191;
          vy[k] = i;
        }
      }
      const int fence = (s + 1) << 11;
      while (n0 < fence) {
        float b2v[KNUM], b3v[KNUM];
#pragma unroll
        for (int k = 0; k < KNUM; ++k)
          b2v[k] = shr1(yp[k], (k == 0) ? p1 : rl63(yp[k - 1]));
#pragma unroll
        for (int k = 0; k < KNUM; ++k)
          b3v[k] = shr1(b2v[k], (k == 0) ? p2 : rl63(b2v[k - 1]));
        float p1n = rlv(yp[KNUM - 1], lq1);   // y(C-1) of current chunk
        float p2n = rlv(b2v[KNUM - 1], lq1);  // y(C-2)
#pragma unroll
        for (int k = 0; k < KNUM; ++k) {
          float v = fmaf(c0w, yp[k], xA[k]);
          v = fmaf(c1w, b2v[k], v);
          yp[k] = fmaf(c2w, b3v[k], v);
        }
        p1 = p1n;
        p2 = p2n;
#pragma unroll
        for (int k = 0; k < KNUM; ++k) {
          if (k < KNUM - 1 || wr) yring[vy[k]] = yp[k];
          vy[k] += C;
          if (vy[k] >= 6144) vy[k] -= 6144;
        }
#pragma unroll
        for (int k = 0; k < KNUM; ++k) {
          xA[k] = xB[k];
          xB[k] = xC[k];
          xC[k] = xD[k];
          xD[k] = xbuf[vx[k]];
          vx[k] = (vx[k] + C) & 8191;
        }
        n0 += C;
      }
    } else {
      const int ht = t - 64;
      if (s >= 1) {
        const int sb = (s - 1) << 11;
        const int slot = ((s - 1) % 3) << 11;
        for (int i = ht; i < 2048; i += 192) yg[sb + i] = yring[slot + i];
      }
      const int ls = s + 3;
      if (ls <= 15) {
        const int xo = ls << 11;
        for (int i = ht; i < 2048; i += 192) xbuf[(xo + i) & 8191] = xg[xo + i];
      }
    }
  }
  __syncthreads();
  // segment 15 lives in ring slot 0 (30720 mod 6144 == 0)
  for (int i = t; i < 2048; i += 256) yg[(15 << 11) + i] = yring[i];
  __syncthreads();
}

// 8-band resonator group: exact affine scan (uniform M^128 multiplier),
// accumulate gained sum into out (plain RMW; same thread owns same elems).
template <bool ACC>
__device__ void body_group(int grp, const float* __restrict__ xin_b,
                           float* __restrict__ out_b,
                           const float* __restrict__ gains, int t,
                           float (*lc0)[8], float (*lc1)[8]) {
  const int lane = t & 63, wid = t >> 6;
  __syncthreads();  // lc0/lc1 reuse guard across groups

  float A1[8], A2[8], B0[8], GN[8];
#pragma unroll
  for (int j = 0; j < 8; ++j) {
    int k = grp * 8 + j;
    // fc = 80 * 100^(k/23)
    float fc = 80.0f * exp2f((float)k * (6.64385618977472436f / 23.0f));
    float w = 2.0f * PI_F * fc / FS_F;
    float r = expf(-PI_F * fc / (10.0f * FS_F));
    A1[j] = -2.0f * r * cosf(w);
    A2[j] = r * r;
    B0[j] = 1.0f - r;
    GN[j] = gains[k];
  }

  const float4* x4 = (const float4*)(xin_b + t * 128);
  float cv0[8], cv1[8];
#pragma unroll
  for (int j = 0; j < 8; ++j) cv0[j] = cv1[j] = 0.0f;
  for (int i = 0; i < 32; ++i) {
    float4 xv = x4[i];
#pragma unroll
    for (int e = 0; e < 4; ++e) {
      float xi = e == 0 ? xv.x : e == 1 ? xv.y : e == 2 ? xv.z : xv.w;
#pragma unroll
      for (int j = 0; j < 8; ++j) {
        float nc = fmaf(B0[j], xi, -fmaf(A1[j], cv0[j], A2[j] * cv1[j]));
        cv1[j] = cv0[j];
        cv0[j] = nc;
      }
    }
  }
  // Q = M^128 by 7 squarings of M = [[-a1,-a2],[1,0]]
  float Q00[8], Q01[8], Q10[8], Q11[8];
#pragma unroll
  for (int j = 0; j < 8; ++j) {
    Q00[j] = -A1[j]; Q01[j] = -A2[j]; Q10[j] = 1.0f; Q11[j] = 0.0f;
  }
  for (int q = 0; q < 7; ++q) {
#pragma unroll
    for (int j = 0; j < 8; ++j) {
      float n00 = fmaf(Q00[j], Q00[j], Q01[j] * Q10[j]);
      float n01 = fmaf(Q00[j], Q01[j], Q01[j] * Q11[j]);
      float n10 = fmaf(Q10[j], Q00[j], Q11[j] * Q10[j]);
      float n11 = fmaf(Q10[j], Q01[j], Q11[j] * Q11[j]);
      Q00[j] = n00; Q01[j] = n01; Q10[j] = n10; Q11[j] = n11;
    }
  }
  float T00[8], T01[8], T10[8], T11[8];
#pragma unroll
  for (int j = 0; j < 8; ++j) {
    T00[j] = Q00[j]; T01[j] = Q01[j]; T10[j] = Q10[j]; T11[j] = Q11[j];
  }
  for (int off = 1; off <= 32; off <<= 1) {
#pragma unroll
    for (int j = 0; j < 8; ++j) {
      float u0 = __shfl_up(cv0[j], off);
      float u1 = __shfl_up(cv1[j], off);
      if (lane >= off) {
        float nc0 = fmaf(Q00[j], u0, fmaf(Q01[j], u1, cv0[j]));
        float nc1 = fmaf(Q10[j], u0, fmaf(Q11[j], u1, cv1[j]));
        cv0[j] = nc0;
        cv1[j] = nc1;
      }
      float n00 = fmaf(Q00[j], Q00[j], Q01[j] * Q10[j]);
      float n01 = fmaf(Q00[j], Q01[j], Q01[j] * Q11[j]);
      float n10 = fmaf(Q10[j], Q00[j], Q11[j] * Q10[j]);
      float n11 = fmaf(Q10[j], Q01[j], Q11[j] * Q11[j]);
      Q00[j] = n00; Q01[j] = n01; Q10[j] = n10; Q11[j] = n11;
    }
  }
  if (lane == 63) {
#pragma unroll
    for (int j = 0; j < 8; ++j) {
      lc0[wid][j] = cv0[j];
      lc1[wid][j] = cv1[j];
    }
  }
  __syncthreads();
  float car0[8], car1[8];
#pragma unroll
  for (int j = 0; j < 8; ++j) car0[j] = car1[j] = 0.0f;
  for (int v = 0; v < wid; ++v) {
#pragma unroll
    for (int j = 0; j < 8; ++j) {
      float n0c = fmaf(Q00[j], car0[j], fmaf(Q01[j], car1[j], lc0[v][j]));
      float n1c = fmaf(Q10[j], car0[j], fmaf(Q11[j], car1[j], lc1[v][j]));
      car0[j] = n0c;
      car1[j] = n1c;
    }
  }
  float R00[8], R01[8], R10[8], R11[8];
#pragma unroll
  for (int j = 0; j < 8; ++j) {
    R00[j] = 1.0f; R01[j] = 0.0f; R10[j] = 0.0f; R11[j] = 1.0f;
  }
  for (int bit = 0; bit < 6; ++bit) {
    bool on = (lane >> bit) & 1;
#pragma unroll
    for (int j = 0; j < 8; ++j) {
      if (on) {
        float n00 = fmaf(T00[j], R00[j], T01[j] * R10[j]);
        float n01 = fmaf(T00[j], R01[j], T01[j] * R11[j]);
        float n10 = fmaf(T10[j], R00[j], T11[j] * R10[j]);
        float n11 = fmaf(T10[j], R01[j], T11[j] * R11[j]);
        R00[j] = n00; R01[j] = n01; R10[j] = n10; R11[j] = n11;
      }
      float s00 = fmaf(T00[j], T00[j], T01[j] * T10[j]);
      float s01 = fmaf(T00[j], T01[j], T01[j] * T11[j]);
      float s10 = fmaf(T10[j], T00[j], T11[j] * T10[j]);
      float s11 = fmaf(T10[j], T01[j], T11[j] * T11[j]);
      T00[j] = s00; T01[j] = s01; T10[j] = s10; T11[j] = s11;
    }
  }
  float y1[8], y2[8];
#pragma unroll
  for (int j = 0; j < 8; ++j) {
    float e0 = __shfl_up(cv0[j], 1);
    float e1 = __shfl_up(cv1[j], 1);
    if (lane == 0) {
      e0 = 0.0f;
      e1 = 0.0f;
    }
    y1[j] = fmaf(R00[j], car0[j], fmaf(R01[j], car1[j], e0));
    y2[j] = fmaf(R10[j], car0[j], fmaf(R11[j], car1[j], e1));
  }
  float4* p4 = (float4*)(out_b + t * 128);
  for (int i = 0; i < 32; ++i) {
    float4 xv = x4[i];
    float4 ov;
#pragma unroll
    for (int e = 0; e < 4; ++e) {
      float xi = e == 0 ? xv.x : e == 1 ? xv.y : e == 2 ? xv.z : xv.w;
      float acc = 0.0f;
#pragma unroll
      for (int j = 0; j < 8; ++j) {
        float yv = fmaf(B0[j], xi, -fmaf(A1[j], y1[j], A2[j] * y2[j]));
        y2[j] = y1[j];
        y1[j] = yv;
        acc = fmaf(GN[j], yv, acc);
      }
      if (e == 0) ov.x = acc;
      else if (e == 1) ov.y = acc;
      else if (e == 2) ov.z = acc;
      else ov.w = acc;
    }
    if (ACC) {
      float4 pv = p4[i];
      ov.x += pv.x; ov.y += pv.y; ov.z += pv.z; ov.w += pv.w;
    }
    p4[i] = ov;
  }
}

// ONE kernel, one block per batch: preLP -> KS -> postLP -> body(3 groups).
// LDS: xbuf[0..8191], yring[8192..14335], lws[14336..14343], lc0/lc1 extra.
__global__ void __launch_bounds__(256, 1) synth_fused(
    const float* __restrict__ exc, const float* __restrict__ pitch,
    const float* __restrict__ w1, const float* __restrict__ b1,
    const float* __restrict__ w2, const float* __restrict__ b2,
    const float* __restrict__ eg, const float* __restrict__ gains,
    float* __restrict__ buf0, float* __restrict__ buf1,
    float* __restrict__ out) {
  const int b = blockIdx.x;
  const int t = threadIdx.x;
  __shared__ float lds[14344];
  __shared__ float lc0[4][8], lc1[4][8];
  float* xbuf = lds;
  float* yring = lds + 8192;
  float* lws = lds + 14336;

  BParams P = compute_params(b, pitch, w1, b1, w2, b2);

  if (b == 0 && t < 64) {
    int bb = (t < 8) ? t : 0;
    BParams Q = compute_params(bb, pitch, w1, b1, w2, b2);
    float slc = 0.0f, slm = 0.0f, slp = 0.0f;
    for (int i = 0; i < 8; ++i) {
      slc += rlv(Q.lc, i);
      slm += rlv(Q.lm, i);
      slp += rlv(Q.lp, i);
    }
    if (t == 0) {
      out[8 * NSAMP + 0] = slc / 8.0f;
      out[8 * NSAMP + 1] = slm / 8.0f;
      out[8 * NSAMP + 2] = slp / 8.0f;
    }
  }

  // phase A: pre-LP exc -> buf0
  lpc_scan2(exc + b * NSAMP, buf0 + b * NSAMP, eg[0] * P.alpha, 1.0f - P.alpha,
            t, lws);
  __syncthreads();

  const float* xg = buf0 + b * NSAMP;
  float* yg = buf1 + b * NSAMP;
  // preamble: x segments 0..2 into xbuf (ks_run's s=0 barrier publishes)
  for (int i = t; i < 6144; i += 256) xbuf[i] = xg[i];

  const int C = P.Di;  // 66..735 given pitch in [60,660]
  const float c0w = P.g * (1.0f - P.s) * (1.0f - P.fr);
  const float c1w = P.g * ((1.0f - P.s) * P.fr + P.s * (1.0f - P.fr));
  const float c2w = P.g * P.s * P.fr;
  const int knum = (C + 63) >> 6;

  switch (knum) {
    case 1:  ks_run<1>(xg, yg, xbuf, yring, t, C, c0w, c1w, c2w); break;
    case 2:  ks_run<2>(xg, yg, xbuf, yring, t, C, c0w, c1w, c2w); break;
    case 3:  ks_run<3>(xg, yg, xbuf, yring, t, C, c0w, c1w, c2w); break;
    case 4:  ks_run<4>(xg, yg, xbuf, yring, t, C, c0w, c1w, c2w); break;
    case 5:  ks_run<5>(xg, yg, xbuf, yring, t, C, c0w, c1w, c2w); break;
    case 6:  ks_run<6>(xg, yg, xbuf, yring, t, C, c0w, c1w, c2w); break;
    case 7:  ks_run<7>(xg, yg, xbuf, yring, t, C, c0w, c1w, c2w); break;
    case 8:  ks_run<8>(xg, yg, xbuf, yring, t, C, c0w, c1w, c2w); break;
    case 9:  ks_run<9>(xg, yg, xbuf, yring, t, C, c0w, c1w, c2w); break;
    case 10: ks_run<10>(xg, yg, xbuf, yring, t, C, c0w, c1w, c2w); break;
    case 11: ks_run<11>(xg, yg, xbuf, yring, t, C, c0w, c1w, c2w); break;
    default: ks_run<12>(xg, yg, xbuf, yring, t, C, c0w, c1w, c2w); break;
  }

  // phase C: post-LP buf1 -> buf0 (string)
  lpc_scan2(buf1 + b * NSAMP, buf0 + b * NSAMP, P.alpha_p, 1.0f - P.alpha_p, t,
            lws);
  __syncthreads();  // drain phase-C stores; buf0 visible block-wide

  // phase D: body, 24 bands in 3 register-reusing groups of 8
  body_group<false>(0, buf0 + b * NSAMP, out + b * NSAMP, gains, t, lc0, lc1);
  body_group<true>(1, buf0 + b * NSAMP, out + b * NSAMP, gains, t, lc0, lc1);
  body_group<true>(2, buf0 + b * NSAMP, out + b * NSAMP, gains, t, lc0, lc1);
}

extern "C" void kernel_launch(void* const* d_in, const int* in_sizes, int n_in,
                              void* d_out, int out_size, void* d_ws, size_t ws_size,
                              hipStream_t stream) {
  const float* exc = (const float*)d_in[0];
  const float* pitch = (const float*)d_in[1];
  const float* w1 = (const float*)d_in[2];
  const float* b1 = (const float*)d_in[3];
  const float* w2 = (const float*)d_in[4];
  const float* b2 = (const float*)d_in[5];
  const float* eg = (const float*)d_in[6];
  const float* bg = (const float*)d_in[7];
  float* out = (float*)d_out;
  float* buf0 = (float*)d_ws;      // 8*NSAMP: exc_f, then post-LP string
  float* buf1 = buf0 + 8 * NSAMP;  // 8*NSAMP: KS output

  hipLaunchKernelGGL(synth_fused, dim3(8), dim3(256), 0, stream, exc, pitch,
                     w1, b1, w2, b2, eg, bg, buf0, buf1, out);
}

// Round 6
// 171.792 us; speedup vs baseline: 1.3129x; 1.3129x over previous
//
#include <hip/hip_runtime.h>
#include <math.h>

#define NSAMP 32768
#define FS_F 44100.0f
#define PI_F 3.14159265358979323846f
#define T1 2048    // k1 KS slice length (16 slices/batch)
#define T2 4096    // k2 body slice length (8 slices/batch)
#define WIN2 12288 // k2 body window = 48 * 256 (>= 8192 resonator warm-up)
#define PLP_WU 256 // postLP warm-up samples

struct BParams {
  float alpha, alpha_p;
  float fr, g, s;
  int Di;
  float lc, lm, lp;
};

__device__ inline float sigmoidf_(float x) { return 1.0f / (1.0f + expf(-x)); }

__device__ inline BParams compute_params(int b, const float* __restrict__ pitch,
                                         const float* __restrict__ w1,
                                         const float* __restrict__ b1,
                                         const float* __restrict__ w2,
                                         const float* __restrict__ b2) {
  BParams P;
  float p = pitch[b];
  float h[16];
#pragma unroll
  for (int i = 0; i < 16; ++i) {
    float v = fmaf(p, w1[i], b1[i]);
    h[i] = v > 0.0f ? v : 0.0f;
  }
  float m[3];
#pragma unroll
  for (int j = 0; j < 3; ++j) {
    float acc = b2[j];
#pragma unroll
    for (int i = 0; i < 16; ++i) acc = fmaf(h[i], w2[j * 16 + i], acc);
    m[j] = acc;
  }
  P.lc = fminf(fmaxf(m[0], -2.0f), 2.5f);
  P.lm = fminf(fmaxf(m[1], -2.5f), 0.0f);
  P.lp = fminf(fmaxf(m[2], -4.0f), 4.0f);
  P.g = 0.999f * sigmoidf_(P.lc);
  P.s = sigmoidf_(P.lm);
  float f0 = fmaxf(p, 60.0f);
  float D = fminf(fmaxf(FS_F / f0, 2.0f), 735.0f);
  int Di = (int)floorf(D);
  P.fr = D - (float)Di;
  P.Di = Di;
  float mult = fminf(fmaxf(2.0f + 6.0f * (f0 - 60.0f) / 600.0f, 2.0f), 8.0f);
  float cutoff = fminf(2.0f * PI_F * f0 * mult / FS_F, PI_F * 0.9f);
  P.alpha = 1.0f - expf(-cutoff);
  float cpost = fminf(PI_F * sigmoidf_(P.lp), PI_F * 0.99f);
  P.alpha_p = 1.0f - expf(-cpost);
  return P;
}

// lane helpers (wave64)
__device__ inline float rl63(float v) {
  return __int_as_float(__builtin_amdgcn_readlane(__float_as_int(v), 63));
}
__device__ inline float rlv(float v, int l) {
  return __int_as_float(__builtin_amdgcn_readlane(__float_as_int(v), l));
}
// whole-wave shift right by 1; lane 0 takes `bnd` (uniform value)
__device__ inline float shr1(float v, float bnd) {
  return __int_as_float(__builtin_amdgcn_update_dpp(
      __float_as_int(bnd), __float_as_int(v), 0x138 /*wave_shr:1*/, 0xf, 0xf,
      false));
}

__device__ inline void band_coef(int k, float& a1, float& a2, float& b0) {
  float fc = 80.0f * exp2f((float)k * (6.64385618977472436f / 23.0f));
  float w = 2.0f * PI_F * fc / FS_F;
  float r = expf(-PI_F * fc / (10.0f * FS_F));
  a1 = -2.0f * r * cosf(w);
  a2 = r * r;
  b0 = 1.0f - r;
}

// Exact one-pole IIR y[n]=scale*x[n]+c*y[n-1] over NSAMP, 256 thr (proven R4).
__device__ inline void lpc_scan2(const float* __restrict__ in,
                                 float* __restrict__ out, float scale, float c,
                                 int t, float* lws) {
  const int lane = t & 63, wid = t >> 6;
  float c2v = c * c, c4 = c2v * c2v, c8 = c4 * c4;
  float m1 = c8, m2 = m1 * m1, m4 = m2 * m2, m8 = m4 * m4, m16 = m8 * m8,
        m32 = m16 * m16;
  float c512 = m32 * m32;
  float c2048 = c512 * c512;
  c2048 *= c2048;
  float l2c = log2f(c);
  float c8lane = exp2f((float)(8 * lane) * l2c);
  float cgk = exp2f((float)(8 * t) * l2c);
  float vrun = 0.0f;
  const float4* in4 = (const float4*)in;
  float4* out4 = (float4*)out;
  for (int tile = 0; tile < 16; ++tile) {
    __syncthreads();
    float4 xa = in4[(tile << 9) + 2 * t];
    float4 xb = in4[(tile << 9) + 2 * t + 1];
    float S = 0.0f;
    S = fmaf(c, S, scale * xa.x); S = fmaf(c, S, scale * xa.y);
    S = fmaf(c, S, scale * xa.z); S = fmaf(c, S, scale * xa.w);
    S = fmaf(c, S, scale * xb.x); S = fmaf(c, S, scale * xb.y);
    S = fmaf(c, S, scale * xb.z); S = fmaf(c, S, scale * xb.w);
    float Sw = S, u;
    u = __shfl_up(Sw, 1);  if (lane >= 1)  Sw = fmaf(m1, u, Sw);
    u = __shfl_up(Sw, 2);  if (lane >= 2)  Sw = fmaf(m2, u, Sw);
    u = __shfl_up(Sw, 4);  if (lane >= 4)  Sw = fmaf(m4, u, Sw);
    u = __shfl_up(Sw, 8);  if (lane >= 8)  Sw = fmaf(m8, u, Sw);
    u = __shfl_up(Sw, 16); if (lane >= 16) Sw = fmaf(m16, u, Sw);
    u = __shfl_up(Sw, 32); if (lane >= 32) Sw = fmaf(m32, u, Sw);
    if (lane == 63) lws[wid] = Sw;
    __syncthreads();
    float a0 = lws[0], a1w = lws[1], a2w = lws[2], a3w = lws[3];
    float carry = (wid == 1)   ? a0
                  : (wid == 2) ? fmaf(c512, a0, a1w)
                  : (wid == 3) ? fmaf(c512, fmaf(c512, a0, a1w), a2w)
                               : 0.0f;
    float Sprev = __shfl_up(Sw, 1);
    float Sex = (lane == 0) ? 0.0f : Sprev;
    Sex = fmaf(c8lane, carry, Sex);
    float v = fmaf(cgk, vrun, Sex);
    float4 ya, yb;
    v = fmaf(c, v, scale * xa.x); ya.x = v;
    v = fmaf(c, v, scale * xa.y); ya.y = v;
    v = fmaf(c, v, scale * xa.z); ya.z = v;
    v = fmaf(c, v, scale * xa.w); ya.w = v;
    v = fmaf(c, v, scale * xb.x); yb.x = v;
    v = fmaf(c, v, scale * xb.y); yb.y = v;
    v = fmaf(c, v, scale * xb.z); yb.z = v;
    v = fmaf(c, v, scale * xb.w); yb.w = v;
    out4[(tile << 9) + 2 * t] = ya;
    out4[(tile << 9) + 2 * t + 1] = yb;
    float tS = fmaf(c512, fmaf(c512, fmaf(c512, a0, a1w), a2w), a3w);
    vrun = fmaf(c2048, vrun, tS);
  }
}

// Same one-pole scan, variable range [s2, s2+nt*2048) from global (guarded at
// NSAMP) into LDS sl[idx = n - s2]. s2 multiple of 4.
__device__ inline void lpc_lds(const float* __restrict__ xg,
                               float* __restrict__ sl, int s2, int nt,
                               float scale, float c, int t, float* lws) {
  const int lane = t & 63, wid = t >> 6;
  float c2v = c * c, c4 = c2v * c2v, c8 = c4 * c4;
  float m1 = c8, m2 = m1 * m1, m4 = m2 * m2, m8 = m4 * m4, m16 = m8 * m8,
        m32 = m16 * m16;
  float c512 = m32 * m32;
  float c2048 = c512 * c512;
  c2048 *= c2048;
  float l2c = log2f(c);
  float c8lane = exp2f((float)(8 * lane) * l2c);
  float cgk = exp2f((float)(8 * t) * l2c);
  float vrun = 0.0f;
  for (int tile = 0; tile < nt; ++tile) {
    __syncthreads();
    int g0 = s2 + (tile << 11) + 8 * t;
    float4 xa = make_float4(0.f, 0.f, 0.f, 0.f);
    float4 xb = make_float4(0.f, 0.f, 0.f, 0.f);
    if (g0 + 3 < NSAMP) xa = *(const float4*)&xg[g0];
    if (g0 + 7 < NSAMP) xb = *(const float4*)&xg[g0 + 4];
    float S = 0.0f;
    S = fmaf(c, S, scale * xa.x); S = fmaf(c, S, scale * xa.y);
    S = fmaf(c, S, scale * xa.z); S = fmaf(c, S, scale * xa.w);
    S = fmaf(c, S, scale * xb.x); S = fmaf(c, S, scale * xb.y);
    S = fmaf(c, S, scale * xb.z); S = fmaf(c, S, scale * xb.w);
    float Sw = S, u;
    u = __shfl_up(Sw, 1);  if (lane >= 1)  Sw = fmaf(m1, u, Sw);
    u = __shfl_up(Sw, 2);  if (lane >= 2)  Sw = fmaf(m2, u, Sw);
    u = __shfl_up(Sw, 4);  if (lane >= 4)  Sw = fmaf(m4, u, Sw);
    u = __shfl_up(Sw, 8);  if (lane >= 8)  Sw = fmaf(m8, u, Sw);
    u = __shfl_up(Sw, 16); if (lane >= 16) Sw = fmaf(m16, u, Sw);
    u = __shfl_up(Sw, 32); if (lane >= 32) Sw = fmaf(m32, u, Sw);
    if (lane == 63) lws[wid] = Sw;
    __syncthreads();
    float a0 = lws[0], a1w = lws[1], a2w = lws[2], a3w = lws[3];
    float carry = (wid == 1)   ? a0
                  : (wid == 2) ? fmaf(c512, a0, a1w)
                  : (wid == 3) ? fmaf(c512, fmaf(c512, a0, a1w), a2w)
                               : 0.0f;
    float Sprev = __shfl_up(Sw, 1);
    float Sex = (lane == 0) ? 0.0f : Sprev;
    Sex = fmaf(c8lane, carry, Sex);
    float v = fmaf(cgk, vrun, Sex);
    int o = g0 - s2;
    float4 ya, yb;
    v = fmaf(c, v, scale * xa.x); ya.x = v;
    v = fmaf(c, v, scale * xa.y); ya.y = v;
    v = fmaf(c, v, scale * xa.z); ya.z = v;
    v = fmaf(c, v, scale * xa.w); ya.w = v;
    v = fmaf(c, v, scale * xb.x); yb.x = v;
    v = fmaf(c, v, scale * xb.y); yb.y = v;
    v = fmaf(c, v, scale * xb.z); yb.z = v;
    v = fmaf(c, v, scale * xb.w); yb.w = v;
    *(float4*)&sl[o] = ya;
    *(float4*)&sl[o + 4] = yb;
    float tS = fmaf(c512, fmaf(c512, fmaf(c512, a0, a1w), a2w), a3w);
    vrun = fmaf(c2048, vrun, tS);
  }
}

// ---------------- k0: preLP (exact) + scalar outputs ----------------
__global__ void __launch_bounds__(256) prelp_kernel(
    const float* __restrict__ exc, const float* __restrict__ pitch,
    const float* __restrict__ w1, const float* __restrict__ b1,
    const float* __restrict__ w2, const float* __restrict__ b2,
    const float* __restrict__ eg, float* __restrict__ buf0,
    float* __restrict__ out_scalars) {
  const int b = blockIdx.x, t = threadIdx.x;
  __shared__ float lws[8];
  BParams P = compute_params(b, pitch, w1, b1, w2, b2);
  if (b == 0 && t < 64) {
    int bb = (t < 8) ? t : 0;
    BParams Q = compute_params(bb, pitch, w1, b1, w2, b2);
    float slc = 0.f, slm = 0.f, slp = 0.f;
    for (int i = 0; i < 8; ++i) {
      slc += rlv(Q.lc, i);
      slm += rlv(Q.lm, i);
      slp += rlv(Q.lp, i);
    }
    if (t == 0) {
      out_scalars[0] = slc / 8.0f;
      out_scalars[1] = slm / 8.0f;
      out_scalars[2] = slp / 8.0f;
    }
  }
  lpc_scan2(exc + b * NSAMP, buf0 + b * NSAMP, eg[0] * P.alpha, 1.0f - P.alpha,
            t, lws);
}

// ---------------- k1: KS time-slices with warm-up ----------------
// One block per (batch, slice of 2048). Recurrence starts from zero state at
// s1 = n0 - min(96*Di, n0); only [n0, n0+T1) is written to buf1.
template <int KNUM>
__device__ void ks_slice(const float* __restrict__ xg, float* __restrict__ yg,
                         float* xbuf, float* yring, int t, int C, float c0w,
                         float c1w, float c2w, int s1, int n0, int span,
                         int nseg) {
  const int lane = t & 63;
  const int lq1 = (C - 1) - (KNUM - 1) * 64;
  const bool wr = (lane + (KNUM - 1) * 64) < C;
  float yp[KNUM], xA[KNUM], xB[KNUM], xC[KNUM], xD[KNUM];
  int vx[KNUM], vy[KNUM];
  float p1 = 0.0f, p2 = 0.0f;
  int rel = 0;
  for (int s = 0; s < nseg; ++s) {
    __syncthreads();
    if (t < 64) {
      if (s == 0) {
#pragma unroll
        for (int k = 0; k < KNUM; ++k) {
          int i = lane + (k << 6);
          yp[k] = 0.0f;
          xA[k] = xbuf[i];
          xB[k] = xbuf[i + C];
          xC[k] = xbuf[i + 2 * C];
          xD[k] = xbuf[i + 3 * C];
          vx[k] = (i + 4 * C) & 8191;
          vy[k] = i;  // ring index, mod 6144
        }
      }
      int fence = (s + 1) << 11;
      if (fence > span) fence = span;
      while (rel < fence) {
        float b2v[KNUM], b3v[KNUM];
#pragma unroll
        for (int k = 0; k < KNUM; ++k)
          b2v[k] = shr1(yp[k], (k == 0) ? p1 : rl63(yp[k - 1]));
#pragma unroll
        for (int k = 0; k < KNUM; ++k)
          b3v[k] = shr1(b2v[k], (k == 0) ? p2 : rl63(b2v[k - 1]));
        float p1n = rlv(yp[KNUM - 1], lq1);   // y(rel+C-1) pre-update
        float p2n = rlv(b2v[KNUM - 1], lq1);  // y(rel+C-2)
#pragma unroll
        for (int k = 0; k < KNUM; ++k)
          yp[k] = fmaf(c0w, yp[k],
                       fmaf(c2w, b3v[k], fmaf(c1w, b2v[k], xA[k])));
        p1 = p1n;
        p2 = p2n;
#pragma unroll
        for (int k = 0; k < KNUM; ++k) {
          if (k < KNUM - 1 || wr) yring[vy[k]] = yp[k];
          vy[k] += C;
          if (vy[k] >= 6144) vy[k] -= 6144;
        }
#pragma unroll
        for (int k = 0; k < KNUM; ++k) {
          xA[k] = xB[k];
          xB[k] = xC[k];
          xC[k] = xD[k];
          xD[k] = xbuf[vx[k]];
          vx[k] = (vx[k] + C) & 8191;
        }
        rel += C;
      }
    } else {
      const int ht = t - 64;
      if (s >= 1) {
        const int sb = (s - 1) << 11;
        const int slot = ((s - 1) % 3) << 11;
        for (int i = ht; i < 2048; i += 192) {
          int n = s1 + sb + i;
          if (n >= n0) yg[n] = yring[slot + i];
        }
      }
      const int ls = s + 3;
      if (ls < nseg) {
        const int xo = ls << 11;
        for (int i = ht; i < 2048; i += 192) xbuf[(xo + i) & 8191] = xg[xo + i];
      }
    }
  }
  __syncthreads();
  {
    const int sb = (nseg - 1) << 11;
    const int slot = ((nseg - 1) % 3) << 11;
    const int len = span - sb;
    for (int i = t; i < len; i += 256) {
      int n = s1 + sb + i;
      if (n >= n0) yg[n] = yring[slot + i];
    }
  }
}

__global__ void __launch_bounds__(256) ks_kernel(
    const float* __restrict__ pitch, const float* __restrict__ w1,
    const float* __restrict__ b1, const float* __restrict__ w2,
    const float* __restrict__ b2, const float* __restrict__ buf0,
    float* __restrict__ buf1) {
  const int blk = blockIdx.x;
  const int b = blk >> 4, q = blk & 15;
  const int t = threadIdx.x;
  __shared__ float lds[8192 + 6144];
  float* xbuf = lds;
  float* yring = lds + 8192;
  BParams P = compute_params(b, pitch, w1, b1, w2, b2);
  const int C = P.Di;
  const int n0 = q << 11;
  int W = 96 * C;
  if (W > n0) W = n0;
  const int s1 = n0 - W;
  const int span = W + T1;
  const int nseg = (span + 2047) >> 11;
  const float* xg = buf0 + b * NSAMP + s1;
  float* yg = buf1 + b * NSAMP;
  for (int i = t; i < 6144; i += 256) xbuf[i] = xg[i];  // first 3 segments
  const float c0w = P.g * (1.0f - P.s) * (1.0f - P.fr);
  const float c1w = P.g * ((1.0f - P.s) * P.fr + P.s * (1.0f - P.fr));
  const float c2w = P.g * P.s * P.fr;
  switch ((C + 63) >> 6) {
    case 1:  ks_slice<1>(xg, yg, xbuf, yring, t, C, c0w, c1w, c2w, s1, n0, span, nseg); break;
    case 2:  ks_slice<2>(xg, yg, xbuf, yring, t, C, c0w, c1w, c2w, s1, n0, span, nseg); break;
    case 3:  ks_slice<3>(xg, yg, xbuf, yring, t, C, c0w, c1w, c2w, s1, n0, span, nseg); break;
    case 4:  ks_slice<4>(xg, yg, xbuf, yring, t, C, c0w, c1w, c2w, s1, n0, span, nseg); break;
    case 5:  ks_slice<5>(xg, yg, xbuf, yring, t, C, c0w, c1w, c2w, s1, n0, span, nseg); break;
    case 6:  ks_slice<6>(xg, yg, xbuf, yring, t, C, c0w, c1w, c2w, s1, n0, span, nseg); break;
    case 7:  ks_slice<7>(xg, yg, xbuf, yring, t, C, c0w, c1w, c2w, s1, n0, span, nseg); break;
    case 8:  ks_slice<8>(xg, yg, xbuf, yring, t, C, c0w, c1w, c2w, s1, n0, span, nseg); break;
    case 9:  ks_slice<9>(xg, yg, xbuf, yring, t, C, c0w, c1w, c2w, s1, n0, span, nseg); break;
    case 10: ks_slice<10>(xg, yg, xbuf, yring, t, C, c0w, c1w, c2w, s1, n0, span, nseg); break;
    case 11: ks_slice<11>(xg, yg, xbuf, yring, t, C, c0w, c1w, c2w, s1, n0, span, nseg); break;
    default: ks_slice<12>(xg, yg, xbuf, yring, t, C, c0w, c1w, c2w, s1, n0, span, nseg); break;
  }
}

// ---------------- k2: postLP (warm-up, into LDS) + 24-band body ----------------
// One block per (batch, slice of 4096). Body window = 12288 samples ending at
// slice end (zero-state warm-up, r^8192 < 1e-2); exact affine scan inside.
__global__ void __launch_bounds__(256, 1) body_kernel(
    const float* __restrict__ pitch, const float* __restrict__ w1,
    const float* __restrict__ b1, const float* __restrict__ w2,
    const float* __restrict__ b2, const float* __restrict__ gains,
    const float* __restrict__ buf1, float* __restrict__ out) {
  const int blk = blockIdx.x;
  const int b = blk >> 3, q = blk & 7;
  const int t = threadIdx.x;
  const int lane = t & 63, wid = t >> 6;
  __shared__ __align__(16) float sl[14344];
  __shared__ float lws[8];
  __shared__ float lc0[4][8], lc1[4][8];

  BParams P = compute_params(b, pitch, w1, b1, w2, b2);
  const int n0 = q * T2;
  const int base = n0 + T2 - WIN2;  // may be negative
  int s2 = base - PLP_WU;
  if (s2 < 0) s2 = 0;
  const int end = n0 + T2;
  const int nt = (end - s2 + 2047) >> 11;

  // postLP string into sl[n - s2] for n in [s2, s2 + nt*2048)
  lpc_lds(buf1 + b * NSAMP, sl, s2, nt, P.alpha_p, 1.0f - P.alpha_p, t, lws);
  __syncthreads();

  const int tb = base + 48 * t;  // this thread's first sample

  // pass1: offset vectors for all 24 bands over the window (zero init state)
  float A1[24], A2[24], B0[24];
#pragma unroll
  for (int k = 0; k < 24; ++k) band_coef(k, A1[k], A2[k], B0[k]);
  float cv0[24], cv1[24];
#pragma unroll
  for (int k = 0; k < 24; ++k) cv0[k] = cv1[k] = 0.0f;
  for (int i = 0; i < 12; ++i) {
    int n = tb + 4 * i;
    float4 xv = make_float4(0.f, 0.f, 0.f, 0.f);
    if (n >= 0) xv = *(const float4*)&sl[n - s2];
#pragma unroll
    for (int e = 0; e < 4; ++e) {
      float xi = e == 0 ? xv.x : e == 1 ? xv.y : e == 2 ? xv.z : xv.w;
#pragma unroll
      for (int j = 0; j < 24; ++j) {
        float nc = fmaf(B0[j], xi, -fmaf(A1[j], cv0[j], A2[j] * cv1[j]));
        cv1[j] = cv0[j];
        cv0[j] = nc;
      }
    }
  }

  // scans: 3 groups of 8 bands; per-thread multiplier is the uniform M^48
  float y1[24], y2[24];
#pragma unroll
  for (int g = 0; g < 3; ++g) {
    float Q00[8], Q01[8], Q10[8], Q11[8];   // running
    float K00[8], K01[8], K10[8], K11[8];   // M^16
    float T00[8], T01[8], T10[8], T11[8];   // M^48 snapshot
#pragma unroll
    for (int j = 0; j < 8; ++j) {
      Q00[j] = -A1[g * 8 + j];
      Q01[j] = -A2[g * 8 + j];
      Q10[j] = 1.0f;
      Q11[j] = 0.0f;
    }
    for (int sq = 0; sq < 4; ++sq) {  // -> M^16
#pragma unroll
      for (int j = 0; j < 8; ++j) {
        float n00 = fmaf(Q00[j], Q00[j], Q01[j] * Q10[j]);
        float n01 = fmaf(Q00[j], Q01[j], Q01[j] * Q11[j]);
        float n10 = fmaf(Q10[j], Q00[j], Q11[j] * Q10[j]);
        float n11 = fmaf(Q10[j], Q01[j], Q11[j] * Q11[j]);
        Q00[j] = n00; Q01[j] = n01; Q10[j] = n10; Q11[j] = n11;
      }
    }
#pragma unroll
    for (int j = 0; j < 8; ++j) {
      K00[j] = Q00[j]; K01[j] = Q01[j]; K10[j] = Q10[j]; K11[j] = Q11[j];
      float n00 = fmaf(Q00[j], Q00[j], Q01[j] * Q10[j]);  // -> M^32
      float n01 = fmaf(Q00[j], Q01[j], Q01[j] * Q11[j]);
      float n10 = fmaf(Q10[j], Q00[j], Q11[j] * Q10[j]);
      float n11 = fmaf(Q10[j], Q01[j], Q11[j] * Q11[j]);
      // M^48 = M^32 * M^16
      float q00 = fmaf(n00, K00[j], n01 * K10[j]);
      float q01 = fmaf(n00, K01[j], n01 * K11[j]);
      float q10 = fmaf(n10, K00[j], n11 * K10[j]);
      float q11 = fmaf(n10, K01[j], n11 * K11[j]);
      Q00[j] = q00; Q01[j] = q01; Q10[j] = q10; Q11[j] = q11;
      T00[j] = q00; T01[j] = q01; T10[j] = q10; T11[j] = q11;
    }
    // Kogge-Stone within wave (Q squares each step -> ends at M^(48*64))
    for (int off = 1; off <= 32; off <<= 1) {
#pragma unroll
      for (int j = 0; j < 8; ++j) {
        float u0 = __shfl_up(cv0[g * 8 + j], off);
        float u1 = __shfl_up(cv1[g * 8 + j], off);
        if (lane >= off) {
          float nc0 = fmaf(Q00[j], u0, fmaf(Q01[j], u1, cv0[g * 8 + j]));
          float nc1 = fmaf(Q10[j], u0, fmaf(Q11[j], u1, cv1[g * 8 + j]));
          cv0[g * 8 + j] = nc0;
          cv1[g * 8 + j] = nc1;
        }
        float n00 = fmaf(Q00[j], Q00[j], Q01[j] * Q10[j]);
        float n01 = fmaf(Q00[j], Q01[j], Q01[j] * Q11[j]);
        float n10 = fmaf(Q10[j], Q00[j], Q11[j] * Q10[j]);
        float n11 = fmaf(Q10[j], Q01[j], Q11[j] * Q11[j]);
        Q00[j] = n00; Q01[j] = n01; Q10[j] = n10; Q11[j] = n11;
      }
    }
    __syncthreads();  // protect lc reuse from previous group
    if (lane == 63) {
#pragma unroll
      for (int j = 0; j < 8; ++j) {
        lc0[wid][j] = cv0[g * 8 + j];
        lc1[wid][j] = cv1[g * 8 + j];
      }
    }
    __syncthreads();
    float car0[8], car1[8];
#pragma unroll
    for (int j = 0; j < 8; ++j) car0[j] = car1[j] = 0.0f;
    for (int v = 0; v < wid; ++v) {
#pragma unroll
      for (int j = 0; j < 8; ++j) {
        float n0c = fmaf(Q00[j], car0[j], fmaf(Q01[j], car1[j], lc0[v][j]));
        float n1c = fmaf(Q10[j], car0[j], fmaf(Q11[j], car1[j], lc1[v][j]));
        car0[j] = n0c;
        car1[j] = n1c;
      }
    }
    // R = (M^48)^lane via binary expansion
    float R00[8], R01[8], R10[8], R11[8];
#pragma unroll
    for (int j = 0; j < 8; ++j) {
      R00[j] = 1.0f; R01[j] = 0.0f; R10[j] = 0.0f; R11[j] = 1.0f;
    }
    for (int bit = 0; bit < 6; ++bit) {
      bool on = (lane >> bit) & 1;
#pragma unroll
      for (int j = 0; j < 8; ++j) {
        if (on) {
          float n00 = fmaf(T00[j], R00[j], T01[j] * R10[j]);
          float n01 = fmaf(T00[j], R01[j], T01[j] * R11[j]);
          float n10 = fmaf(T10[j], R00[j], T11[j] * R10[j]);
          float n11 = fmaf(T10[j], R01[j], T11[j] * R11[j]);
          R00[j] = n00; R01[j] = n01; R10[j] = n10; R11[j] = n11;
        }
        float s00 = fmaf(T00[j], T00[j], T01[j] * T10[j]);
        float s01 = fmaf(T00[j], T01[j], T01[j] * T11[j]);
        float s10 = fmaf(T10[j], T00[j], T11[j] * T10[j]);
        float s11 = fmaf(T10[j], T01[j], T11[j] * T11[j]);
        T00[j] = s00; T01[j] = s01; T10[j] = s10; T11[j] = s11;
      }
    }
#pragma unroll
    for (int j = 0; j < 8; ++j) {
      float e0 = __shfl_up(cv0[g * 8 + j], 1);
      float e1 = __shfl_up(cv1[g * 8 + j], 1);
      if (lane == 0) { e0 = 0.0f; e1 = 0.0f; }
      y1[g * 8 + j] = fmaf(R00[j], car0[j], fmaf(R01[j], car1[j], e0));
      y2[g * 8 + j] = fmaf(R10[j], car0[j], fmaf(R11[j], car1[j], e1));
    }
  }

  // pass2: replay with seeds, emit gained 24-band sum for n in [n0, n0+T2)
  float GN[24];
#pragma unroll
  for (int k = 0; k < 24; ++k) GN[k] = gains[k];
  float* outb = out + b * NSAMP;
  for (int i = 0; i < 12; ++i) {
    int n = tb + 4 * i;
    float4 xv = make_float4(0.f, 0.f, 0.f, 0.f);
    if (n >= 0) xv = *(const float4*)&sl[n - s2];
    float4 ov;
#pragma unroll
    for (int e = 0; e < 4; ++e) {
      float xi = e == 0 ? xv.x : e == 1 ? xv.y : e == 2 ? xv.z : xv.w;
      float acc = 0.0f;
#pragma unroll
      for (int j = 0; j < 24; ++j) {
        float yv = fmaf(B0[j], xi, -fmaf(A1[j], y1[j], A2[j] * y2[j]));
        y2[j] = y1[j];
        y1[j] = yv;
        acc = fmaf(GN[j], yv, acc);
      }
      if (e == 0) ov.x = acc;
      else if (e == 1) ov.y = acc;
      else if (e == 2) ov.z = acc;
      else ov.w = acc;
    }
    if (n >= n0) *(float4*)&outb[n] = ov;
  }
}

extern "C" void kernel_launch(void* const* d_in, const int* in_sizes, int n_in,
                              void* d_out, int out_size, void* d_ws, size_t ws_size,
                              hipStream_t stream) {
  const float* exc = (const float*)d_in[0];
  const float* pitch = (const float*)d_in[1];
  const float* w1 = (const float*)d_in[2];
  const float* b1 = (const float*)d_in[3];
  const float* w2 = (const float*)d_in[4];
  const float* b2 = (const float*)d_in[5];
  const float* eg = (const float*)d_in[6];
  const float* bg = (const float*)d_in[7];
  float* out = (float*)d_out;
  float* buf0 = (float*)d_ws;                  // 8*NSAMP + 8192 pad (preLP x)
  float* buf1 = buf0 + 8 * NSAMP + 8192;       // 8*NSAMP (KS output)

  hipLaunchKernelGGL(prelp_kernel, dim3(8), dim3(256), 0, stream, exc, pitch,
                     w1, b1, w2, b2, eg, buf0, out + 8 * NSAMP);
  hipLaunchKernelGGL(ks_kernel, dim3(128), dim3(256), 0, stream, pitch, w1, b1,
                     w2, b2, buf0, buf1);
  hipLaunchKernelGGL(body_kernel, dim3(64), dim3(256), 0, stream, pitch, w1,
                     b1, w2, b2, bg, buf1, out);
}

// Round 7
// 150.583 us; speedup vs baseline: 1.4979x; 1.1408x over previous
//
#include <hip/hip_runtime.h>
#include <math.h>

#define NSAMP 32768
#define FS_F 44100.0f
#define PI_F 3.14159265358979323846f
#define T1 1024  // KS slice length (32 slices/batch)
#define T2 4096  // body slice length (8 slices/batch)

struct BParams {
  float alpha, alpha_p;
  float fr, g, s;
  int Di;
  float lc, lm, lp;
};

__device__ inline float sigmoidf_(float x) { return 1.0f / (1.0f + expf(-x)); }

__device__ inline BParams compute_params(int b, const float* __restrict__ pitch,
                                         const float* __restrict__ w1,
                                         const float* __restrict__ b1,
                                         const float* __restrict__ w2,
                                         const float* __restrict__ b2) {
  BParams P;
  float p = pitch[b];
  float h[16];
#pragma unroll
  for (int i = 0; i < 16; ++i) {
    float v = fmaf(p, w1[i], b1[i]);
    h[i] = v > 0.0f ? v : 0.0f;
  }
  float m[3];
#pragma unroll
  for (int j = 0; j < 3; ++j) {
    float acc = b2[j];
#pragma unroll
    for (int i = 0; i < 16; ++i) acc = fmaf(h[i], w2[j * 16 + i], acc);
    m[j] = acc;
  }
  P.lc = fminf(fmaxf(m[0], -2.0f), 2.5f);
  P.lm = fminf(fmaxf(m[1], -2.5f), 0.0f);
  P.lp = fminf(fmaxf(m[2], -4.0f), 4.0f);
  P.g = 0.999f * sigmoidf_(P.lc);
  P.s = sigmoidf_(P.lm);
  float f0 = fmaxf(p, 60.0f);
  float D = fminf(fmaxf(FS_F / f0, 2.0f), 735.0f);
  int Di = (int)floorf(D);
  P.fr = D - (float)Di;
  P.Di = Di;
  float mult = fminf(fmaxf(2.0f + 6.0f * (f0 - 60.0f) / 600.0f, 2.0f), 8.0f);
  float cutoff = fminf(2.0f * PI_F * f0 * mult / FS_F, PI_F * 0.9f);
  P.alpha = 1.0f - expf(-cutoff);
  float cpost = fminf(PI_F * sigmoidf_(P.lp), PI_F * 0.99f);
  P.alpha_p = 1.0f - expf(-cpost);
  return P;
}

// lane helpers (wave64)
__device__ inline float rl63(float v) {
  return __int_as_float(__builtin_amdgcn_readlane(__float_as_int(v), 63));
}
__device__ inline float rlv(float v, int l) {
  return __int_as_float(__builtin_amdgcn_readlane(__float_as_int(v), l));
}
// whole-wave shift right by 1; lane 0 takes `bnd` (uniform value)
__device__ inline float shr1(float v, float bnd) {
  return __int_as_float(__builtin_amdgcn_update_dpp(
      __float_as_int(bnd), __float_as_int(v), 0x138 /*wave_shr:1*/, 0xf, 0xf,
      false));
}

// Workgroup barrier that drains ONLY lgkmcnt (LDS) — does NOT wait for
// in-flight global stores (avoids __syncthreads' vmcnt(0) drain).
__device__ inline void barrier_lgkm() {
  asm volatile("s_waitcnt lgkmcnt(0)\n\ts_barrier" ::: "memory");
}

__device__ inline void band_coef(int k, float& a1, float& a2, float& b0) {
  float fc = 80.0f * exp2f((float)k * (6.64385618977472436f / 23.0f));
  float w = 2.0f * PI_F * fc / FS_F;
  float r = expf(-PI_F * fc / (10.0f * FS_F));
  a1 = -2.0f * r * cosf(w);
  a2 = r * r;
  b0 = 1.0f - r;
}

// Exact one-pole IIR y[n]=scale*x[n]+c*y[n-1] over NSAMP, 256 thr (proven R4).
__device__ inline void lpc_scan2(const float* __restrict__ in,
                                 float* __restrict__ out, float scale, float c,
                                 int t, float* lws) {
  const int lane = t & 63, wid = t >> 6;
  float c2v = c * c, c4 = c2v * c2v, c8 = c4 * c4;
  float m1 = c8, m2 = m1 * m1, m4 = m2 * m2, m8 = m4 * m4, m16 = m8 * m8,
        m32 = m16 * m16;
  float c512 = m32 * m32;
  float c2048 = c512 * c512;
  c2048 *= c2048;
  float l2c = log2f(c);
  float c8lane = exp2f((float)(8 * lane) * l2c);
  float cgk = exp2f((float)(8 * t) * l2c);
  float vrun = 0.0f;
  const float4* in4 = (const float4*)in;
  float4* out4 = (float4*)out;
  for (int tile = 0; tile < 16; ++tile) {
    __syncthreads();
    float4 xa = in4[(tile << 9) + 2 * t];
    float4 xb = in4[(tile << 9) + 2 * t + 1];
    float S = 0.0f;
    S = fmaf(c, S, scale * xa.x); S = fmaf(c, S, scale * xa.y);
    S = fmaf(c, S, scale * xa.z); S = fmaf(c, S, scale * xa.w);
    S = fmaf(c, S, scale * xb.x); S = fmaf(c, S, scale * xb.y);
    S = fmaf(c, S, scale * xb.z); S = fmaf(c, S, scale * xb.w);
    float Sw = S, u;
    u = __shfl_up(Sw, 1);  if (lane >= 1)  Sw = fmaf(m1, u, Sw);
    u = __shfl_up(Sw, 2);  if (lane >= 2)  Sw = fmaf(m2, u, Sw);
    u = __shfl_up(Sw, 4);  if (lane >= 4)  Sw = fmaf(m4, u, Sw);
    u = __shfl_up(Sw, 8);  if (lane >= 8)  Sw = fmaf(m8, u, Sw);
    u = __shfl_up(Sw, 16); if (lane >= 16) Sw = fmaf(m16, u, Sw);
    u = __shfl_up(Sw, 32); if (lane >= 32) Sw = fmaf(m32, u, Sw);
    if (lane == 63) lws[wid] = Sw;
    __syncthreads();
    float a0 = lws[0], a1w = lws[1], a2w = lws[2], a3w = lws[3];
    float carry = (wid == 1)   ? a0
                  : (wid == 2) ? fmaf(c512, a0, a1w)
                  : (wid == 3) ? fmaf(c512, fmaf(c512, a0, a1w), a2w)
                               : 0.0f;
    float Sprev = __shfl_up(Sw, 1);
    float Sex = (lane == 0) ? 0.0f : Sprev;
    Sex = fmaf(c8lane, carry, Sex);
    float v = fmaf(cgk, vrun, Sex);
    float4 ya, yb;
    v = fmaf(c, v, scale * xa.x); ya.x = v;
    v = fmaf(c, v, scale * xa.y); ya.y = v;
    v = fmaf(c, v, scale * xa.z); ya.z = v;
    v = fmaf(c, v, scale * xa.w); ya.w = v;
    v = fmaf(c, v, scale * xb.x); yb.x = v;
    v = fmaf(c, v, scale * xb.y); yb.y = v;
    v = fmaf(c, v, scale * xb.z); yb.z = v;
    v = fmaf(c, v, scale * xb.w); yb.w = v;
    out4[(tile << 9) + 2 * t] = ya;
    out4[(tile << 9) + 2 * t + 1] = yb;
    float tS = fmaf(c512, fmaf(c512, fmaf(c512, a0, a1w), a2w), a3w);
    vrun = fmaf(c2048, vrun, tS);
  }
}

// Same scan over [s2, s2+nt*2048) from global (guarded at NSAMP) into LDS
// sl[n - s2]. s2 multiple of 4.
__device__ inline void lpc_lds(const float* __restrict__ xg,
                               float* __restrict__ sl, int s2, int nt,
                               float scale, float c, int t, float* lws) {
  const int lane = t & 63, wid = t >> 6;
  float c2v = c * c, c4 = c2v * c2v, c8 = c4 * c4;
  float m1 = c8, m2 = m1 * m1, m4 = m2 * m2, m8 = m4 * m4, m16 = m8 * m8,
        m32 = m16 * m16;
  float c512 = m32 * m32;
  float c2048 = c512 * c512;
  c2048 *= c2048;
  float l2c = log2f(c);
  float c8lane = exp2f((float)(8 * lane) * l2c);
  float cgk = exp2f((float)(8 * t) * l2c);
  float vrun = 0.0f;
  for (int tile = 0; tile < nt; ++tile) {
    __syncthreads();
    int g0 = s2 + (tile << 11) + 8 * t;
    float4 xa = make_float4(0.f, 0.f, 0.f, 0.f);
    float4 xb = make_float4(0.f, 0.f, 0.f, 0.f);
    if (g0 + 3 < NSAMP) xa = *(const float4*)&xg[g0];
    if (g0 + 7 < NSAMP) xb = *(const float4*)&xg[g0 + 4];
    float S = 0.0f;
    S = fmaf(c, S, scale * xa.x); S = fmaf(c, S, scale * xa.y);
    S = fmaf(c, S, scale * xa.z); S = fmaf(c, S, scale * xa.w);
    S = fmaf(c, S, scale * xb.x); S = fmaf(c, S, scale * xb.y);
    S = fmaf(c, S, scale * xb.z); S = fmaf(c, S, scale * xb.w);
    float Sw = S, u;
    u = __shfl_up(Sw, 1);  if (lane >= 1)  Sw = fmaf(m1, u, Sw);
    u = __shfl_up(Sw, 2);  if (lane >= 2)  Sw = fmaf(m2, u, Sw);
    u = __shfl_up(Sw, 4);  if (lane >= 4)  Sw = fmaf(m4, u, Sw);
    u = __shfl_up(Sw, 8);  if (lane >= 8)  Sw = fmaf(m8, u, Sw);
    u = __shfl_up(Sw, 16); if (lane >= 16) Sw = fmaf(m16, u, Sw);
    u = __shfl_up(Sw, 32); if (lane >= 32) Sw = fmaf(m32, u, Sw);
    if (lane == 63) lws[wid] = Sw;
    __syncthreads();
    float a0 = lws[0], a1w = lws[1], a2w = lws[2], a3w = lws[3];
    float carry = (wid == 1)   ? a0
                  : (wid == 2) ? fmaf(c512, a0, a1w)
                  : (wid == 3) ? fmaf(c512, fmaf(c512, a0, a1w), a2w)
                               : 0.0f;
    float Sprev = __shfl_up(Sw, 1);
    float Sex = (lane == 0) ? 0.0f : Sprev;
    Sex = fmaf(c8lane, carry, Sex);
    float v = fmaf(cgk, vrun, Sex);
    int o = g0 - s2;
    float4 ya, yb;
    v = fmaf(c, v, scale * xa.x); ya.x = v;
    v = fmaf(c, v, scale * xa.y); ya.y = v;
    v = fmaf(c, v, scale * xa.z); ya.z = v;
    v = fmaf(c, v, scale * xa.w); ya.w = v;
    v = fmaf(c, v, scale * xb.x); yb.x = v;
    v = fmaf(c, v, scale * xb.y); yb.y = v;
    v = fmaf(c, v, scale * xb.z); yb.z = v;
    v = fmaf(c, v, scale * xb.w); yb.w = v;
    *(float4*)&sl[o] = ya;
    *(float4*)&sl[o + 4] = yb;
    float tS = fmaf(c512, fmaf(c512, fmaf(c512, a0, a1w), a2w), a3w);
    vrun = fmaf(c2048, vrun, tS);
  }
}

// ---------------- k0: preLP (exact) + scalar outputs ----------------
__global__ void __launch_bounds__(256) prelp_kernel(
    const float* __restrict__ exc, const float* __restrict__ pitch,
    const float* __restrict__ w1, const float* __restrict__ b1,
    const float* __restrict__ w2, const float* __restrict__ b2,
    const float* __restrict__ eg, float* __restrict__ buf0,
    float* __restrict__ out_scalars) {
  const int b = blockIdx.x, t = threadIdx.x;
  __shared__ float lws[8];
  BParams P = compute_params(b, pitch, w1, b1, w2, b2);
  if (b == 0 && t < 64) {
    int bb = (t < 8) ? t : 0;
    BParams Q = compute_params(bb, pitch, w1, b1, w2, b2);
    float slc = 0.f, slm = 0.f, slp = 0.f;
    for (int i = 0; i < 8; ++i) {
      slc += rlv(Q.lc, i);
      slm += rlv(Q.lm, i);
      slp += rlv(Q.lp, i);
    }
    if (t == 0) {
      out_scalars[0] = slc / 8.0f;
      out_scalars[1] = slm / 8.0f;
      out_scalars[2] = slp / 8.0f;
    }
  }
  lpc_scan2(exc + b * NSAMP, buf0 + b * NSAMP, eg[0] * P.alpha, 1.0f - P.alpha,
            t, lws);
}

// ---------------- k1: KS time-slices ----------------
// KNUM<=3: wave 0 register-resident chunk loop, direct global y stores,
//          per-segment x copy phases by all threads.
// KNUM>=4: slots split across 4 waves; boundary lane62/63 + p1/p2 carried via
//          parity-double-buffered LDS; one lgkm-only barrier per chunk.
template <int KNUM>
__device__ void ks_slice2(const float* __restrict__ xg, float* __restrict__ yg,
                          float* xbuf, float* bnd, int t, int C, float c0w,
                          float c1w, float c2w, int s1, int n0, int end,
                          int span, int nseg) {
  const int lane = t & 63;
  const int wid = t >> 6;
  const int lq1 = (C - 1) - (KNUM - 1) * 64;

  if (KNUM <= 3) {
    float yp[KNUM], xC[KNUM], xN[KNUM];
    float p1 = 0.f, p2 = 0.f;
    int rel = 0;
#pragma unroll
    for (int k = 0; k < KNUM; ++k) { yp[k] = 0.f; xC[k] = 0.f; xN[k] = 0.f; }
    for (int s = 0; s < nseg; ++s) {
      barrier_lgkm();
      if (wid == 0) {
        if (s == 0) {
#pragma unroll
          for (int k = 0; k < KNUM; ++k) {
            int i = lane + (k << 6);
            xC[k] = xbuf[i];
            xN[k] = xbuf[C + i];
          }
        }
        int fence = (s + 1) << 11;
        if (fence > span) fence = span;
        while (rel < fence) {
          float b2v[KNUM], b3v[KNUM];
#pragma unroll
          for (int k = 0; k < KNUM; ++k)
            b2v[k] = shr1(yp[k], (k == 0) ? p1 : rl63(yp[k - 1]));
#pragma unroll
          for (int k = 0; k < KNUM; ++k)
            b3v[k] = shr1(b2v[k], (k == 0) ? p2 : rlv(yp[k - 1], 62));
          float p1n = rlv(yp[KNUM - 1], lq1);
          float p2n = rlv(b2v[KNUM - 1], lq1);
#pragma unroll
          for (int k = 0; k < KNUM; ++k)
            yp[k] = fmaf(c0w, yp[k],
                         fmaf(c2w, b3v[k], fmaf(c1w, b2v[k], xC[k])));
          p1 = p1n;
          p2 = p2n;
#pragma unroll
          for (int k = 0; k < KNUM; ++k) {
            int i = lane + (k << 6);
            int n = s1 + rel + i;
            bool okl = (k < KNUM - 1) || (lane <= lq1);
            if (okl && n >= n0 && n < end) yg[n] = yp[k];
          }
#pragma unroll
          for (int k = 0; k < KNUM; ++k) {
            xC[k] = xN[k];
            xN[k] = xbuf[(rel + 2 * C + lane + (k << 6)) & 8191];
          }
          rel += C;
        }
      }
      barrier_lgkm();
      int ls = s + 3;
      if (ls < nseg) {
        int j = (ls << 11) + 8 * t;
        float4 a = *(const float4*)&xg[j];
        float4 c4 = *(const float4*)&xg[j + 4];
        *(float4*)&xbuf[j & 8191] = a;
        *(float4*)&xbuf[(j + 4) & 8191] = c4;
      }
    }
  } else {
    constexpr int SPW = (KNUM + 3) / 4;
    const int kbase = wid * SPW;
    float yp[SPW], xC[SPW], xN[SPW];
    int rel = 0, par = 0;
#pragma unroll
    for (int kk = 0; kk < SPW; ++kk) { yp[kk] = 0.f; xC[kk] = 0.f; xN[kk] = 0.f; }
    for (int s = 0; s < nseg; ++s) {
      barrier_lgkm();
      if (s == 0) {
#pragma unroll
        for (int kk = 0; kk < SPW; ++kk) {
          int k = kbase + kk;
          if (k < KNUM) {
            int i = lane + (k << 6);
            xC[kk] = xbuf[i];
            xN[kk] = xbuf[C + i];
          }
        }
      }
      int fence = (s + 1) << 11;
      if (fence > span) fence = span;
      while (rel < fence) {
        barrier_lgkm();  // publishes previous iteration's bnd writes
        const int rb = par << 5, wb = rb ^ 32;
        float pbA = 0.f, pbB = 0.f;
        if (kbase == 0) {
          pbA = bnd[rb + 24];
          pbB = bnd[rb + 25];
        } else if (kbase < KNUM) {
          pbA = bnd[rb + (kbase - 1) * 2];
          pbB = bnd[rb + (kbase - 1) * 2 + 1];
        }
        float b2v[SPW], b3v[SPW];
#pragma unroll
        for (int kk = 0; kk < SPW; ++kk) {
          int k = kbase + kk;
          if (k < KNUM)
            b2v[kk] = shr1(yp[kk], (kk == 0) ? pbA : rl63(yp[kk - 1]));
        }
#pragma unroll
        for (int kk = 0; kk < SPW; ++kk) {
          int k = kbase + kk;
          if (k < KNUM)
            b3v[kk] = shr1(b2v[kk], (kk == 0) ? pbB : rlv(yp[kk - 1], 62));
        }
        float p1n = 0.f, p2n = 0.f;
        const bool ownLast = (KNUM - 1 >= kbase) && (KNUM - 1 < kbase + SPW);
        if (ownLast) {
          p1n = rlv(yp[KNUM - 1 - kbase], lq1);
          p2n = rlv(b2v[KNUM - 1 - kbase], lq1);
        }
#pragma unroll
        for (int kk = 0; kk < SPW; ++kk) {
          int k = kbase + kk;
          if (k < KNUM)
            yp[kk] = fmaf(c0w, yp[kk],
                          fmaf(c2w, b3v[kk], fmaf(c1w, b2v[kk], xC[kk])));
        }
#pragma unroll
        for (int kk = 0; kk < SPW; ++kk) {
          int k = kbase + kk;
          if (k < KNUM) {
            int i = lane + (k << 6);
            int n = s1 + rel + i;
            bool okl = (k < KNUM - 1) || (lane <= lq1);
            if (okl && n >= n0 && n < end) yg[n] = yp[kk];
            float h63 = rlv(yp[kk], 63);
            float h62 = rlv(yp[kk], 62);
            if (lane == 0) {
              bnd[wb + k * 2] = h63;
              bnd[wb + k * 2 + 1] = h62;
            }
          }
        }
        if (ownLast && lane == 0) {
          bnd[wb + 24] = p1n;
          bnd[wb + 25] = p2n;
        }
#pragma unroll
        for (int kk = 0; kk < SPW; ++kk) {
          int k = kbase + kk;
          if (k < KNUM) {
            xC[kk] = xN[kk];
            xN[kk] = xbuf[(rel + 2 * C + lane + (k << 6)) & 8191];
          }
        }
        rel += C;
        par ^= 1;
      }
      barrier_lgkm();
      int ls = s + 3;
      if (ls < nseg) {
        int j = (ls << 11) + 8 * t;
        float4 a = *(const float4*)&xg[j];
        float4 c4 = *(const float4*)&xg[j + 4];
        *(float4*)&xbuf[j & 8191] = a;
        *(float4*)&xbuf[(j + 4) & 8191] = c4;
      }
    }
  }
}

__global__ void __launch_bounds__(256) ks_kernel(
    const float* __restrict__ pitch, const float* __restrict__ w1,
    const float* __restrict__ b1, const float* __restrict__ w2,
    const float* __restrict__ b2, const float* __restrict__ buf0,
    float* __restrict__ buf1) {
  const int blk = blockIdx.x;
  const int b = blk >> 5, q = blk & 31;
  const int t = threadIdx.x;
  __shared__ float lds[8192 + 64];
  float* xbuf = lds;
  float* bnd = lds + 8192;
  BParams P = compute_params(b, pitch, w1, b1, w2, b2);
  const int C = P.Di;
  const int n0 = q << 10;
  // adaptive warm-up: g^Wp <= e^-10.5 (capped at 96 periods = R6's level)
  float lg = -logf(P.g);
  int Wp = (int)ceilf(10.5f / fmaxf(lg, 1e-6f));
  if (Wp > 96) Wp = 96;
  if (Wp < 4) Wp = 4;
  int W = Wp * C;
  if (W > n0) W = n0;
  W = (W + 3) & ~3;  // s1 alignment (n0 % 4 == 0, so still <= n0)
  const int s1 = n0 - W;
  const int span = W + T1;
  const int end = n0 + T1;
  const int nseg = (span + 2047) >> 11;
  const float* xg = buf0 + (size_t)b * NSAMP + s1;
  float* yg = buf1 + (size_t)b * NSAMP;
  for (int j = 8 * t; j < 6144; j += 2048) {
    float4 a = *(const float4*)&xg[j];
    float4 c4 = *(const float4*)&xg[j + 4];
    *(float4*)&xbuf[j] = a;
    *(float4*)&xbuf[j + 4] = c4;
  }
  if (t < 64) bnd[t] = 0.0f;
  const float c0w = P.g * (1.0f - P.s) * (1.0f - P.fr);
  const float c1w = P.g * ((1.0f - P.s) * P.fr + P.s * (1.0f - P.fr));
  const float c2w = P.g * P.s * P.fr;
  switch ((C + 63) >> 6) {
    case 2:  ks_slice2<2>(xg, yg, xbuf, bnd, t, C, c0w, c1w, c2w, s1, n0, end, span, nseg); break;
    case 3:  ks_slice2<3>(xg, yg, xbuf, bnd, t, C, c0w, c1w, c2w, s1, n0, end, span, nseg); break;
    case 4:  ks_slice2<4>(xg, yg, xbuf, bnd, t, C, c0w, c1w, c2w, s1, n0, end, span, nseg); break;
    case 5:  ks_slice2<5>(xg, yg, xbuf, bnd, t, C, c0w, c1w, c2w, s1, n0, end, span, nseg); break;
    case 6:  ks_slice2<6>(xg, yg, xbuf, bnd, t, C, c0w, c1w, c2w, s1, n0, end, span, nseg); break;
    case 7:  ks_slice2<7>(xg, yg, xbuf, bnd, t, C, c0w, c1w, c2w, s1, n0, end, span, nseg); break;
    case 8:  ks_slice2<8>(xg, yg, xbuf, bnd, t, C, c0w, c1w, c2w, s1, n0, end, span, nseg); break;
    case 9:  ks_slice2<9>(xg, yg, xbuf, bnd, t, C, c0w, c1w, c2w, s1, n0, end, span, nseg); break;
    case 10: ks_slice2<10>(xg, yg, xbuf, bnd, t, C, c0w, c1w, c2w, s1, n0, end, span, nseg); break;
    case 11: ks_slice2<11>(xg, yg, xbuf, bnd, t, C, c0w, c1w, c2w, s1, n0, end, span, nseg); break;
    default: ks_slice2<12>(xg, yg, xbuf, bnd, t, C, c0w, c1w, c2w, s1, n0, end, span, nseg); break;
  }
}

// ---------------- k2: postLP (LDS) + 24-band body, grouped ----------------
// One block per (batch, slice of 4096). Window = 8192 (4096 warm-up + 4096
// out), 32 samples/thread; per-group (8 bands) full pipeline to cap VGPRs.
__global__ void __launch_bounds__(256, 1) body_kernel(
    const float* __restrict__ pitch, const float* __restrict__ w1,
    const float* __restrict__ b1, const float* __restrict__ w2,
    const float* __restrict__ b2, const float* __restrict__ gains,
    const float* __restrict__ buf1, float* __restrict__ out) {
  const int blk = blockIdx.x;
  const int b = blk >> 3, q = blk & 7;
  const int t = threadIdx.x;
  const int lane = t & 63, wid = t >> 6;
  __shared__ __align__(16) float sl[10240];
  __shared__ float lws[8];
  __shared__ float lc0[4][8], lc1[4][8];

  BParams P = compute_params(b, pitch, w1, b1, w2, b2);
  const int n0 = q * T2;
  const int base = n0 - 4096;
  int s2 = base - 256;  // postLP warm-up
  if (s2 < 0) s2 = 0;
  const int end = n0 + T2;
  const int nt = (end - s2 + 2047) >> 11;  // <= 5

  lpc_lds(buf1 + (size_t)b * NSAMP, sl, s2, nt, P.alpha_p, 1.0f - P.alpha_p, t,
          lws);
  __syncthreads();

  const int tb = base + 32 * t;
  float4 acc[8];
#pragma unroll
  for (int i = 0; i < 8; ++i) acc[i] = make_float4(0.f, 0.f, 0.f, 0.f);

  for (int g = 0; g < 3; ++g) {
    float A1[8], A2[8], B0[8], GN[8];
#pragma unroll
    for (int j = 0; j < 8; ++j) {
      int k = g * 8 + j;
      band_coef(k, A1[j], A2[j], B0[j]);
      GN[j] = gains[k];
    }
    // pass1: offset vector over this thread's 32 samples (zero init)
    float cv0[8], cv1[8];
#pragma unroll
    for (int j = 0; j < 8; ++j) cv0[j] = cv1[j] = 0.f;
    for (int i = 0; i < 8; ++i) {
      int n = tb + 4 * i;
      float4 xv = make_float4(0.f, 0.f, 0.f, 0.f);
      if (n >= 0) xv = *(const float4*)&sl[n - s2];
#pragma unroll
      for (int e = 0; e < 4; ++e) {
        float xi = e == 0 ? xv.x : e == 1 ? xv.y : e == 2 ? xv.z : xv.w;
#pragma unroll
        for (int j = 0; j < 8; ++j) {
          float nc = fmaf(B0[j], xi, -fmaf(A1[j], cv0[j], A2[j] * cv1[j]));
          cv1[j] = cv0[j];
          cv0[j] = nc;
        }
      }
    }
    // Q = M^32 via 5 squarings; T snapshot
    float Q00[8], Q01[8], Q10[8], Q11[8];
#pragma unroll
    for (int j = 0; j < 8; ++j) {
      Q00[j] = -A1[j]; Q01[j] = -A2[j]; Q10[j] = 1.f; Q11[j] = 0.f;
    }
    for (int sq = 0; sq < 5; ++sq) {
#pragma unroll
      for (int j = 0; j < 8; ++j) {
        float n00 = fmaf(Q00[j], Q00[j], Q01[j] * Q10[j]);
        float n01 = fmaf(Q00[j], Q01[j], Q01[j] * Q11[j]);
        float n10 = fmaf(Q10[j], Q00[j], Q11[j] * Q10[j]);
        float n11 = fmaf(Q10[j], Q01[j], Q11[j] * Q11[j]);
        Q00[j] = n00; Q01[j] = n01; Q10[j] = n10; Q11[j] = n11;
      }
    }
    float T00[8], T01[8], T10[8], T11[8];
#pragma unroll
    for (int j = 0; j < 8; ++j) {
      T00[j] = Q00[j]; T01[j] = Q01[j]; T10[j] = Q10[j]; T11[j] = Q11[j];
    }
    // Kogge-Stone within wave (Q squares each step)
    for (int off = 1; off <= 32; off <<= 1) {
#pragma unroll
      for (int j = 0; j < 8; ++j) {
        float u0 = __shfl_up(cv0[j], off);
        float u1 = __shfl_up(cv1[j], off);
        if (lane >= off) {
          float nc0 = fmaf(Q00[j], u0, fmaf(Q01[j], u1, cv0[j]));
          float nc1 = fmaf(Q10[j], u0, fmaf(Q11[j], u1, cv1[j]));
          cv0[j] = nc0;
          cv1[j] = nc1;
        }
        float n00 = fmaf(Q00[j], Q00[j], Q01[j] * Q10[j]);
        float n01 = fmaf(Q00[j], Q01[j], Q01[j] * Q11[j]);
        float n10 = fmaf(Q10[j], Q00[j], Q11[j] * Q10[j]);
        float n11 = fmaf(Q10[j], Q01[j], Q11[j] * Q11[j]);
        Q00[j] = n00; Q01[j] = n01; Q10[j] = n10; Q11[j] = n11;
      }
    }
    __syncthreads();  // lc reuse guard
    if (lane == 63) {
#pragma unroll
      for (int j = 0; j < 8; ++j) {
        lc0[wid][j] = cv0[j];
        lc1[wid][j] = cv1[j];
      }
    }
    __syncthreads();
    float car0[8], car1[8];
#pragma unroll
    for (int j = 0; j < 8; ++j) car0[j] = car1[j] = 0.f;
    for (int v = 0; v < wid; ++v) {
#pragma unroll
      for (int j = 0; j < 8; ++j) {
        float n0c = fmaf(Q00[j], car0[j], fmaf(Q01[j], car1[j], lc0[v][j]));
        float n1c = fmaf(Q10[j], car0[j], fmaf(Q11[j], car1[j], lc1[v][j]));
        car0[j] = n0c;
        car1[j] = n1c;
      }
    }
    // R = (M^32)^lane
    float R00[8], R01[8], R10[8], R11[8];
#pragma unroll
    for (int j = 0; j < 8; ++j) {
      R00[j] = 1.f; R01[j] = 0.f; R10[j] = 0.f; R11[j] = 1.f;
    }
    for (int bit = 0; bit < 6; ++bit) {
      bool on = (lane >> bit) & 1;
#pragma unroll
      for (int j = 0; j < 8; ++j) {
        if (on) {
          float n00 = fmaf(T00[j], R00[j], T01[j] * R10[j]);
          float n01 = fmaf(T00[j], R01[j], T01[j] * R11[j]);
          float n10 = fmaf(T10[j], R00[j], T11[j] * R10[j]);
          float n11 = fmaf(T10[j], R01[j], T11[j] * R11[j]);
          R00[j] = n00; R01[j] = n01; R10[j] = n10; R11[j] = n11;
        }
        float s00 = fmaf(T00[j], T00[j], T01[j] * T10[j]);
        float s01 = fmaf(T00[j], T01[j], T01[j] * T11[j]);
        float s10 = fmaf(T10[j], T00[j], T11[j] * T10[j]);
        float s11 = fmaf(T10[j], T01[j], T11[j] * T11[j]);
        T00[j] = s00; T01[j] = s01; T10[j] = s10; T11[j] = s11;
      }
    }
    float y1[8], y2[8];
#pragma unroll
    for (int j = 0; j < 8; ++j) {
      float e0 = __shfl_up(cv0[j], 1);
      float e1 = __shfl_up(cv1[j], 1);
      if (lane == 0) { e0 = 0.f; e1 = 0.f; }
      y1[j] = fmaf(R00[j], car0[j], fmaf(R01[j], car1[j], e0));
      y2[j] = fmaf(R10[j], car0[j], fmaf(R11[j], car1[j], e1));
    }
    // pass2: output threads only (tb >= n0 <=> t >= 128)
    if (t >= 128) {
      for (int i = 0; i < 8; ++i) {
        float4 xv = *(const float4*)&sl[tb - s2 + 4 * i];
        float4 ov = acc[i];
#pragma unroll
        for (int e = 0; e < 4; ++e) {
          float xi = e == 0 ? xv.x : e == 1 ? xv.y : e == 2 ? xv.z : xv.w;
          float a = 0.f;
#pragma unroll
          for (int j = 0; j < 8; ++j) {
            float yv = fmaf(B0[j], xi, -fmaf(A1[j], y1[j], A2[j] * y2[j]));
            y2[j] = y1[j];
            y1[j] = yv;
            a = fmaf(GN[j], yv, a);
          }
          if (e == 0) ov.x += a;
          else if (e == 1) ov.y += a;
          else if (e == 2) ov.z += a;
          else ov.w += a;
        }
        acc[i] = ov;
      }
    }
  }
  if (t >= 128) {
    float* outb = out + (size_t)b * NSAMP;
#pragma unroll
    for (int i = 0; i < 8; ++i) *(float4*)&outb[tb + 4 * i] = acc[i];
  }
}

extern "C" void kernel_launch(void* const* d_in, const int* in_sizes, int n_in,
                              void* d_out, int out_size, void* d_ws, size_t ws_size,
                              hipStream_t stream) {
  const float* exc = (const float*)d_in[0];
  const float* pitch = (const float*)d_in[1];
  const float* w1 = (const float*)d_in[2];
  const float* b1 = (const float*)d_in[3];
  const float* w2 = (const float*)d_in[4];
  const float* b2 = (const float*)d_in[5];
  const float* eg = (const float*)d_in[6];
  const float* bg = (const float*)d_in[7];
  float* out = (float*)d_out;
  float* buf0 = (float*)d_ws;             // 8*NSAMP + 8192 pad (preLP output)
  float* buf1 = buf0 + 8 * NSAMP + 8192;  // 8*NSAMP (KS output)

  hipLaunchKernelGGL(prelp_kernel, dim3(8), dim3(256), 0, stream, exc, pitch,
                     w1, b1, w2, b2, eg, buf0, out + 8 * NSAMP);
  hipLaunchKernelGGL(ks_kernel, dim3(256), dim3(256), 0, stream, pitch, w1, b1,
                     w2, b2, buf0, buf1);
  hipLaunchKernelGGL(body_kernel, dim3(64), dim3(256), 0, stream, pitch, w1,
                     b1, w2, b2, bg, buf1, out);
}